// Round 3
// baseline (100.448 us; speedup 1.0000x reference)
//
#include <hip/hip_runtime.h>

namespace {
constexpr int NPER = 512;   // blocks per segment
constexpr int UU   = 4;     // units per block
constexpr int KK   = 16;    // k
constexpr int NB   = 4096;  // total blocks
constexpr int NK   = NB * KK;
constexpr int SFL  = 12;    // floats per candidate in LDS (48B, 16B-aligned, ~2-way conflict = free)

// One 64-bit compare-exchange step of a wave min-reduction via DPP.
// Lanes with no valid source (bound_ctrl=false / row_mask off) receive `old`
// = 0xFFFFFFFF in both halves = u64 identity for min.
template <int CTRL, int RM>
__device__ __forceinline__ void dpp_min_step(unsigned& lo, unsigned& hi) {
    unsigned lo2 = (unsigned)__builtin_amdgcn_update_dpp(
        (int)0xFFFFFFFF, (int)lo, CTRL, RM, 0xF, false);
    unsigned hi2 = (unsigned)__builtin_amdgcn_update_dpp(
        (int)0xFFFFFFFF, (int)hi, CTRL, RM, 0xF, false);
    unsigned long long a = ((unsigned long long)hi << 32) | lo;
    unsigned long long b = ((unsigned long long)hi2 << 32) | lo2;
    if (b < a) { lo = lo2; hi = hi2; }
}

// Wave-wide u64 min -> uniform value (SGPR pair via readlane 63).
__device__ __forceinline__ unsigned long long wave_min_u64(unsigned long long v) {
    unsigned lo = (unsigned)v, hi = (unsigned)(v >> 32);
    dpp_min_step<0x111, 0xF>(lo, hi);  // row_shr:1
    dpp_min_step<0x112, 0xF>(lo, hi);  // row_shr:2
    dpp_min_step<0x114, 0xF>(lo, hi);  // row_shr:4
    dpp_min_step<0x118, 0xF>(lo, hi);  // row_shr:8
    dpp_min_step<0x142, 0xA>(lo, hi);  // row_bcast:15 -> rows 1,3
    dpp_min_step<0x143, 0xC>(lo, hi);  // row_bcast:31 -> rows 2,3
    unsigned mlo = (unsigned)__builtin_amdgcn_readlane((int)lo, 63);
    unsigned mhi = (unsigned)__builtin_amdgcn_readlane((int)hi, 63);
    return ((unsigned long long)mhi << 32) | mlo;
}

__global__ __launch_bounds__(512, 8) void knn_edge_kernel(const float* __restrict__ unit_pos,
                                                          int* __restrict__ out) {
    __shared__ float sp[NPER * SFL];                 // 24576 B
    __shared__ unsigned long long mb[4][2 * KK];     // per-row 32 winner keys, 1024 B

    const int wg  = blockIdx.x;        // 1024 WGs; 4 rows x 2 waves each
    const int seg = (wg * 4) >> 9;     // / NPER
    const int tid = threadIdx.x;

    // Stage segment positions: 512 blocks x 12 floats, float4 both sides.
    {
        const float4* g4 = reinterpret_cast<const float4*>(
            unit_pos + (size_t)seg * NPER * UU * 3);
        float4* s4 = reinterpret_cast<float4*>(sp);
        #pragma unroll
        for (int j = 0; j < 3; ++j) s4[tid + 512 * j] = g4[tid + 512 * j];
    }
    __syncthreads();

    const int wave = tid >> 6;
    const int lane = tid & 63;
    const int row_local = (wg * 4 + (wave >> 1)) & (NPER - 1);
    const int half = wave & 1;          // which 256 candidates this wave owns

    // Row block's 4 units + squared norms (uniform LDS broadcast reads).
    // Exact reference f32 arithmetic: left-to-right adds, no FMA contraction.
    float xi[UU], yi[UU], zi[UU], ai[UU];
    {
        const float4 r0 = *reinterpret_cast<const float4*>(&sp[row_local * SFL + 0]);
        const float4 r1 = *reinterpret_cast<const float4*>(&sp[row_local * SFL + 4]);
        const float4 r2 = *reinterpret_cast<const float4*>(&sp[row_local * SFL + 8]);
        xi[0] = r0.x; yi[0] = r0.y; zi[0] = r0.z;
        xi[1] = r0.w; yi[1] = r1.x; zi[1] = r1.y;
        xi[2] = r1.z; yi[2] = r1.w; zi[2] = r2.x;
        xi[3] = r2.y; yi[3] = r2.z; zi[3] = r2.w;
        #pragma unroll
        for (int u = 0; u < UU; ++u)
            ai[u] = __fadd_rn(__fadd_rn(__fmul_rn(xi[u], xi[u]),
                                        __fmul_rn(yi[u], yi[u])),
                              __fmul_rn(zi[u], zi[u]));
    }

    // Each lane owns candidates c = half*256 + lane + 64*t, t=0..3.
    unsigned long long key[4];
    #pragma unroll
    for (int t = 0; t < 4; ++t) {
        const int c = half * 256 + lane + 64 * t;
        const float4 q0 = *reinterpret_cast<const float4*>(&sp[c * SFL + 0]);
        const float4 q1 = *reinterpret_cast<const float4*>(&sp[c * SFL + 4]);
        const float4 q2 = *reinterpret_cast<const float4*>(&sp[c * SFL + 8]);
        float xj[UU], yj[UU], zj[UU];
        xj[0] = q0.x; yj[0] = q0.y; zj[0] = q0.z;
        xj[1] = q0.w; yj[1] = q1.x; zj[1] = q1.y;
        xj[2] = q1.z; yj[2] = q1.w; zj[2] = q2.x;
        xj[3] = q2.y; yj[3] = q2.z; zj[3] = q2.w;
        float m = __builtin_inff();
        #pragma unroll
        for (int v = 0; v < UU; ++v) {
            const float aj = __fadd_rn(__fadd_rn(__fmul_rn(xj[v], xj[v]),
                                                 __fmul_rn(yj[v], yj[v])),
                                       __fmul_rn(zj[v], zj[v]));
            #pragma unroll
            for (int u = 0; u < UU; ++u) {
                float dot = __fadd_rn(__fadd_rn(__fmul_rn(xi[u], xj[v]),
                                                __fmul_rn(yi[u], yj[v])),
                                      __fmul_rn(zi[u], zj[v]));
                float d2 = __fsub_rn(__fadd_rn(ai[u], aj), __fmul_rn(2.0f, dot));
                d2 = fmaxf(d2, 0.0f);
                m  = fminf(m, d2);
            }
        }
        // Same rounded sqrt as reference (collapses near-ties identically;
        // min/sqrt commute by weak monotonicity).
        float dist = __fsqrt_rn(m);
        key[t] = ((unsigned long long)__float_as_uint(dist) << 32) | (unsigned int)c;
    }

    // 16x: wave-wide min of (dist,col) keys via DPP; lane `it` records winner.
    unsigned long long mykey = 0xFFFFFFFFFFFFFFFFull;
    #pragma unroll
    for (int it = 0; it < KK; ++it) {
        unsigned long long lm = key[0];
        #pragma unroll
        for (int t = 1; t < 4; ++t) lm = key[t] < lm ? key[t] : lm;
        const unsigned long long m = wave_min_u64(lm);  // uniform
        if (lane == it) mykey = m;
        #pragma unroll
        for (int t = 0; t < 4; ++t)
            if (key[t] == m) key[t] = 0xFFFFFFFFFFFFFFFFull;
    }
    if (lane < KK) mb[wave >> 1][half * KK + lane] = mykey;
    __syncthreads();

    // Merge: wave w (<4) rank-merges row w's 32 sorted winners -> top 16.
    if (wave < 4) {
        const int r_global = seg * NPER + ((wg * 4 + wave) & (NPER - 1));
        if (lane < 2 * KK) {
            const unsigned long long k = mb[wave][lane];
            int rank = 0;
            #pragma unroll 8
            for (int m = 0; m < 2 * KK; ++m)
                rank += (mb[wave][m] < k) ? 1 : 0;   // keys distinct -> exact rank
            if (rank < KK) {
                const int c = (int)(unsigned)(k & 0xFFFFFFFFull);
                out[NK + r_global * KK + rank] = seg * NPER + c;   // col_o
            }
        }
        if (lane < KK) {
            const int o = r_global * KK + lane;
            out[o]          = r_global;   // row_o
            out[2 * NK + o] = 0;          // attr
        }
    }
}
} // namespace

extern "C" void kernel_launch(void* const* d_in, const int* in_sizes, int n_in,
                              void* d_out, int out_size, void* d_ws, size_t ws_size,
                              hipStream_t stream) {
    const float* unit_pos = (const float*)d_in[0];
    int* out = (int*)d_out;
    hipLaunchKernelGGL(knn_edge_kernel, dim3(NB / 4), dim3(512), 0, stream,
                       unit_pos, out);
}

// Round 4
// 27.898 us; speedup vs baseline: 3.6005x; 3.6005x over previous
//
#include <hip/hip_runtime.h>

namespace {
constexpr int NPER = 512;    // blocks per segment
constexpr int UU   = 4;      // units per block
constexpr int KK   = 16;     // k
constexpr int NB   = 4096;   // total blocks
constexpr int NK   = NB * KK;
constexpr int STRIDE = 13;   // floats per candidate row in LDS; odd stride ->
                             // bank = (13*l)%32 bijective on 32 -> 2-way = free (m136)

// One 64-bit compare-exchange step of a wave min-reduction via DPP.
// Invalid-source lanes receive `old` = all-ones = u64 min identity.
template <int CTRL, int RM>
__device__ __forceinline__ void dpp_min_step(unsigned& lo, unsigned& hi) {
    unsigned lo2 = (unsigned)__builtin_amdgcn_update_dpp(
        (int)0xFFFFFFFF, (int)lo, CTRL, RM, 0xF, false);
    unsigned hi2 = (unsigned)__builtin_amdgcn_update_dpp(
        (int)0xFFFFFFFF, (int)hi, CTRL, RM, 0xF, false);
    unsigned long long a = ((unsigned long long)hi << 32) | lo;
    unsigned long long b = ((unsigned long long)hi2 << 32) | lo2;
    if (b < a) { lo = lo2; hi = hi2; }
}

// Wave-wide u64 min -> uniform value (readlane 63).
__device__ __forceinline__ unsigned long long wave_min_u64(unsigned long long v) {
    unsigned lo = (unsigned)v, hi = (unsigned)(v >> 32);
    dpp_min_step<0x111, 0xF>(lo, hi);  // row_shr:1
    dpp_min_step<0x112, 0xF>(lo, hi);  // row_shr:2
    dpp_min_step<0x114, 0xF>(lo, hi);  // row_shr:4
    dpp_min_step<0x118, 0xF>(lo, hi);  // row_shr:8
    dpp_min_step<0x142, 0xA>(lo, hi);  // row_bcast:15 -> rows 1,3
    dpp_min_step<0x143, 0xC>(lo, hi);  // row_bcast:31 -> rows 2,3
    unsigned mlo = (unsigned)__builtin_amdgcn_readlane((int)lo, 63);
    unsigned mhi = (unsigned)__builtin_amdgcn_readlane((int)hi, 63);
    return ((unsigned long long)mhi << 32) | mlo;
}

// NO min-waves hint: R3 showed __launch_bounds__(512,8) clamps VGPRs (->32)
// and spills ~173 MB of scratch traffic per dispatch. Let the allocator float;
// the working set (~50 regs) fits the 64-VGPR / 8-waves-per-SIMD step naturally.
__global__ __launch_bounds__(512) void knn_edge_kernel(const float* __restrict__ unit_pos,
                                                       int* __restrict__ out) {
    __shared__ float sp[NPER * STRIDE];              // 26624 B
    __shared__ unsigned long long mb[4][2 * KK];     // per-row 32 winner keys

    const int wg  = blockIdx.x;        // 1024 WGs; 4 rows x 2 waves each
    const int seg = (wg * 4) >> 9;     // / NPER
    const int tid = threadIdx.x;

    // Stage segment positions: float4 global loads, scalar stride-13 LDS stores.
    {
        const float4* g4 = reinterpret_cast<const float4*>(
            unit_pos + (size_t)seg * NPER * UU * 3);
        #pragma unroll
        for (int j = 0; j < 3; ++j) {
            const int i = tid + 512 * j;       // float4 index 0..1535
            const float4 v = g4[i];
            const int c = i / 3;
            const int part = (i - 3 * c) * 4;
            float* d = &sp[c * STRIDE + part];
            d[0] = v.x; d[1] = v.y; d[2] = v.z; d[3] = v.w;
        }
    }
    __syncthreads();

    const int wave = tid >> 6;
    const int lane = tid & 63;
    const int row_local = (wg * 4 + (wave >> 1)) & (NPER - 1);
    const int half = wave & 1;          // which 256 candidates this wave owns

    // Row block's 4 units + squared norms (uniform broadcast LDS reads).
    // Exact reference f32 arithmetic: left-to-right adds, no FMA contraction.
    float xi[UU], yi[UU], zi[UU], ai[UU];
    #pragma unroll
    for (int u = 0; u < UU; ++u) {
        const float* p = &sp[row_local * STRIDE + u * 3];
        xi[u] = p[0]; yi[u] = p[1]; zi[u] = p[2];
        ai[u] = __fadd_rn(__fadd_rn(__fmul_rn(xi[u], xi[u]),
                                    __fmul_rn(yi[u], yi[u])),
                          __fmul_rn(zi[u], zi[u]));
    }

    // Each lane owns candidates c = half*256 + lane + 64*t, t=0..3.
    unsigned long long key[4];
    #pragma unroll
    for (int t = 0; t < 4; ++t) {
        const int c = half * 256 + lane + 64 * t;
        const float* p = &sp[c * STRIDE];
        float xj[UU], yj[UU], zj[UU];
        #pragma unroll
        for (int v = 0; v < UU; ++v) {
            xj[v] = p[v * 3 + 0]; yj[v] = p[v * 3 + 1]; zj[v] = p[v * 3 + 2];
        }
        float m = __builtin_inff();
        #pragma unroll
        for (int v = 0; v < UU; ++v) {
            const float aj = __fadd_rn(__fadd_rn(__fmul_rn(xj[v], xj[v]),
                                                 __fmul_rn(yj[v], yj[v])),
                                       __fmul_rn(zj[v], zj[v]));
            #pragma unroll
            for (int u = 0; u < UU; ++u) {
                float dot = __fadd_rn(__fadd_rn(__fmul_rn(xi[u], xj[v]),
                                                __fmul_rn(yi[u], yj[v])),
                                      __fmul_rn(zi[u], zj[v]));
                float d2 = __fsub_rn(__fadd_rn(ai[u], aj), __fmul_rn(2.0f, dot));
                d2 = fmaxf(d2, 0.0f);
                m  = fminf(m, d2);
            }
        }
        // Same rounded sqrt as reference (collapses near-ties identically;
        // min/sqrt commute by weak monotonicity).
        float dist = __fsqrt_rn(m);
        key[t] = ((unsigned long long)__float_as_uint(dist) << 32) | (unsigned int)c;
    }

    // 16x: wave-wide min via DPP; lane `it` records winner; invalidate winner.
    unsigned long long mykey = 0xFFFFFFFFFFFFFFFFull;
    #pragma unroll
    for (int it = 0; it < KK; ++it) {
        unsigned long long lm = key[0];
        #pragma unroll
        for (int t = 1; t < 4; ++t) lm = key[t] < lm ? key[t] : lm;
        const unsigned long long m = wave_min_u64(lm);  // uniform
        if (lane == it) mykey = m;
        #pragma unroll
        for (int t = 0; t < 4; ++t)
            if (key[t] == m) key[t] = 0xFFFFFFFFFFFFFFFFull;
    }
    if (lane < KK) mb[wave >> 1][half * KK + lane] = mykey;
    __syncthreads();

    // Merge: wave w (<4) rank-merges row w's 32 sorted winners -> top 16.
    // Keys are globally distinct (col in low bits) -> ranks are exact.
    if (wave < 4) {
        const int r_global = seg * NPER + ((wg * 4 + wave) & (NPER - 1));
        if (lane < 2 * KK) {
            const unsigned long long k = mb[wave][lane];
            int rank = 0;
            #pragma unroll 8
            for (int m = 0; m < 2 * KK; ++m)
                rank += (mb[wave][m] < k) ? 1 : 0;
            if (rank < KK) {
                const int c = (int)(unsigned)(k & 0xFFFFFFFFull);
                out[NK + r_global * KK + rank] = seg * NPER + c;   // col_o
            }
        }
        if (lane < KK) {
            const int o = r_global * KK + lane;
            out[o]          = r_global;   // row_o
            out[2 * NK + o] = 0;          // attr
        }
    }
}
} // namespace

extern "C" void kernel_launch(void* const* d_in, const int* in_sizes, int n_in,
                              void* d_out, int out_size, void* d_ws, size_t ws_size,
                              hipStream_t stream) {
    const float* unit_pos = (const float*)d_in[0];
    int* out = (int*)d_out;
    hipLaunchKernelGGL(knn_edge_kernel, dim3(NB / 4), dim3(512), 0, stream,
                       unit_pos, out);
}

// Round 5
// 24.000 us; speedup vs baseline: 4.1853x; 1.1624x over previous
//
#include <hip/hip_runtime.h>

namespace {
constexpr int NPER = 512;    // blocks per segment
constexpr int UU   = 4;      // units per block
constexpr int KK   = 16;     // k
constexpr int NB   = 4096;   // total blocks
constexpr int NK   = NB * KK;
constexpr int DST  = 9;      // doubles per candidate (72B): 6 data + 3 pad

// ---- packed dual-f32 (VOP3P). Each half is an exact IEEE _rn f32 op. ----
union pk2 { double d; float f[2]; unsigned u[2]; };

__device__ __forceinline__ double mkpk(float lo, float hi) {
    pk2 t; t.f[0] = lo; t.f[1] = hi; return t.d;
}
__device__ __forceinline__ double pk_mul(double a, double b) {
    double r; asm("v_pk_mul_f32 %0, %1, %2" : "=v"(r) : "v"(a), "v"(b)); return r;
}
__device__ __forceinline__ double pk_add(double a, double b) {
    double r; asm("v_pk_add_f32 %0, %1, %2" : "=v"(r) : "v"(a), "v"(b)); return r;
}
__device__ __forceinline__ double pk_fma(double a, double b, double c) {
    double r; asm("v_pk_fma_f32 %0, %1, %2, %3" : "=v"(r) : "v"(a), "v"(b), "v"(c)); return r;
}

// ---- u64 wave min via DPP (R2-verified) ----
template <int CTRL, int RM>
__device__ __forceinline__ void dpp_min_step(unsigned& lo, unsigned& hi) {
    unsigned lo2 = (unsigned)__builtin_amdgcn_update_dpp(
        (int)0xFFFFFFFF, (int)lo, CTRL, RM, 0xF, false);
    unsigned hi2 = (unsigned)__builtin_amdgcn_update_dpp(
        (int)0xFFFFFFFF, (int)hi, CTRL, RM, 0xF, false);
    unsigned long long a = ((unsigned long long)hi << 32) | lo;
    unsigned long long b = ((unsigned long long)hi2 << 32) | lo2;
    if (b < a) { lo = lo2; hi = hi2; }
}
__device__ __forceinline__ unsigned long long wave_min_u64(unsigned long long v) {
    unsigned lo = (unsigned)v, hi = (unsigned)(v >> 32);
    dpp_min_step<0x111, 0xF>(lo, hi);  // row_shr:1
    dpp_min_step<0x112, 0xF>(lo, hi);  // row_shr:2
    dpp_min_step<0x114, 0xF>(lo, hi);  // row_shr:4
    dpp_min_step<0x118, 0xF>(lo, hi);  // row_shr:8
    dpp_min_step<0x142, 0xA>(lo, hi);  // row_bcast:15 -> rows 1,3
    dpp_min_step<0x143, 0xC>(lo, hi);  // row_bcast:31 -> rows 2,3
    unsigned mlo = (unsigned)__builtin_amdgcn_readlane((int)lo, 63);
    unsigned mhi = (unsigned)__builtin_amdgcn_readlane((int)hi, 63);
    return ((unsigned long long)mhi << 32) | mlo;
}

__global__ __launch_bounds__(256) void knn_edge_kernel(const float* __restrict__ unit_pos,
                                                       int* __restrict__ out) {
    __shared__ double spd[NPER * DST];               // 36864 B
    float* sfl = reinterpret_cast<float*>(spd);

    const int wg  = blockIdx.x;        // 1024 WGs; 4 rows (waves) each
    const int seg = (wg * 4) >> 9;     // / NPER
    const int tid = threadIdx.x;

    // Stage segment positions, pair-SoA per candidate:
    // float layout [x0 x1 x2 x3 | y0..y3 | z0..z3 | pad x6], stride 18 floats.
    // Global is AoS: float j of candidate c has unit u=j/3, axis=j%3.
    {
        const float4* g4 = reinterpret_cast<const float4*>(
            unit_pos + (size_t)seg * NPER * UU * 3);
        #pragma unroll
        for (int jj = 0; jj < 6; ++jj) {
            const int i4 = tid + 256 * jj;     // float4 index 0..1535
            const float4 v = g4[i4];
            const int c = i4 / 3;
            const int rem = (i4 - 3 * c) * 4;  // 0, 4, or 8
            const float vv[4] = {v.x, v.y, v.z, v.w};
            #pragma unroll
            for (int e = 0; e < 4; ++e) {
                const int j = rem + e, u = j / 3, ax = j - 3 * u;
                sfl[c * (2 * DST) + ax * 4 + u] = vv[e];
            }
        }
    }
    __syncthreads();

    const int wave = tid >> 6;
    const int lane = tid & 63;
    const int r_local  = (wg * 4 + wave) & (NPER - 1);
    const int r_global = seg * NPER + r_local;

    // Row units duplicated into pk pairs + norms (uniform broadcast reads).
    double xi_p[UU], yi_p[UU], zi_p[UU], ai_p[UU];
    {
        const float* rp = &sfl[r_local * (2 * DST)];
        #pragma unroll
        for (int u = 0; u < UU; ++u) {
            const float x = rp[0 * 4 + u], y = rp[1 * 4 + u], z = rp[2 * 4 + u];
            const float a = __fadd_rn(__fadd_rn(__fmul_rn(x, x), __fmul_rn(y, y)),
                                      __fmul_rn(z, z));
            xi_p[u] = mkpk(x, x); yi_p[u] = mkpk(y, y);
            zi_p[u] = mkpk(z, z); ai_p[u] = mkpk(a, a);
        }
    }
    const double m2 = mkpk(-2.0f, -2.0f);

    // Each lane owns candidates c = lane + 64*t. Packed math: halves are the
    // reference's exact f32 ops (left-assoc adds; fma(dot,-2,sum) ==
    // fsub(sum, fmul(2,dot)) since 2*dot is exact).
    unsigned long long key[8];
    #pragma unroll
    for (int t = 0; t < 8; ++t) {
        const int c = lane + 64 * t;
        const double* cp = &spd[c * DST];
        const double x01 = cp[0], x23 = cp[1];
        const double y01 = cp[2], y23 = cp[3];
        const double z01 = cp[4], z23 = cp[5];
        const double aj01 = pk_add(pk_add(pk_mul(x01, x01), pk_mul(y01, y01)),
                                   pk_mul(z01, z01));
        const double aj23 = pk_add(pk_add(pk_mul(x23, x23), pk_mul(y23, y23)),
                                   pk_mul(z23, z23));
        pk2 h[8];
        #pragma unroll
        for (int u = 0; u < UU; ++u) {
            const double dot01 = pk_add(pk_add(pk_mul(xi_p[u], x01),
                                               pk_mul(yi_p[u], y01)),
                                        pk_mul(zi_p[u], z01));
            const double dot23 = pk_add(pk_add(pk_mul(xi_p[u], x23),
                                               pk_mul(yi_p[u], y23)),
                                        pk_mul(zi_p[u], z23));
            h[u].d     = pk_fma(dot01, m2, pk_add(ai_p[u], aj01));
            h[4 + u].d = pk_fma(dot23, m2, pk_add(ai_p[u], aj23));
        }
        // Exact min over 16 d2 (tree order irrelevant), deferred clamp:
        // max(min_i d2_i, 0) == min_i max(d2_i, 0) bit-exactly.
        const float m01 = fminf(fminf(h[0].f[0], h[0].f[1]),
                                fminf(h[1].f[0], h[1].f[1]));
        const float m23 = fminf(fminf(h[2].f[0], h[2].f[1]),
                                fminf(h[3].f[0], h[3].f[1]));
        const float m45 = fminf(fminf(h[4].f[0], h[4].f[1]),
                                fminf(h[5].f[0], h[5].f[1]));
        const float m67 = fminf(fminf(h[6].f[0], h[6].f[1]),
                                fminf(h[7].f[0], h[7].f[1]));
        float m = fminf(fminf(m01, m23), fminf(m45, m67));
        m = fmaxf(m, 0.0f);
        // Same rounded sqrt as reference (collapses near-ties identically).
        const float dist = __fsqrt_rn(m);
        key[t] = ((unsigned long long)__float_as_uint(dist) << 32) | (unsigned)c;
    }

    // 16x: wave-wide min via DPP; lane `it` records winner; invalidate winner.
    int mycol = 0;
    #pragma unroll
    for (int it = 0; it < KK; ++it) {
        unsigned long long lm = key[0];
        #pragma unroll
        for (int t = 1; t < 8; ++t) lm = key[t] < lm ? key[t] : lm;
        const unsigned long long m = wave_min_u64(lm);  // uniform
        if (lane == it) mycol = (int)(unsigned)(m & 0xffffffffull);
        #pragma unroll
        for (int t = 0; t < 8; ++t)
            if (key[t] == m) key[t] = 0xFFFFFFFFFFFFFFFFull;
    }

    // Outputs concatenated flat: row_o[65536], col_o[65536], attr[65536] (int32).
    if (lane < KK) {
        const int o = r_global * KK + lane;
        out[o]          = r_global;
        out[NK + o]     = (seg * NPER) + mycol;
        out[2 * NK + o] = 0;
    }
}
} // namespace

extern "C" void kernel_launch(void* const* d_in, const int* in_sizes, int n_in,
                              void* d_out, int out_size, void* d_ws, size_t ws_size,
                              hipStream_t stream) {
    const float* unit_pos = (const float*)d_in[0];
    int* out = (int*)d_out;
    hipLaunchKernelGGL(knn_edge_kernel, dim3(NB / 4), dim3(256), 0, stream,
                       unit_pos, out);
}

// Round 7
// 22.524 us; speedup vs baseline: 4.4597x; 1.0656x over previous
//
#include <hip/hip_runtime.h>

namespace {
constexpr int NPER = 512;    // blocks per segment
constexpr int UU   = 4;      // units per block
constexpr int KK   = 16;     // k
constexpr int NB   = 4096;   // total blocks
constexpr int NK   = NB * KK;
constexpr int DST  = 9;      // doubles per candidate (72B): 6 data + 3 pad

// ---- packed dual-f32 (VOP3P). Each half is an exact IEEE _rn f32 op. ----
union pk2 { double d; float f[2]; unsigned u[2]; };

__device__ __forceinline__ double mkpk(float lo, float hi) {
    pk2 t; t.f[0] = lo; t.f[1] = hi; return t.d;
}
__device__ __forceinline__ double pk_mul(double a, double b) {
    double r; asm("v_pk_mul_f32 %0, %1, %2" : "=v"(r) : "v"(a), "v"(b)); return r;
}
__device__ __forceinline__ double pk_add(double a, double b) {
    double r; asm("v_pk_add_f32 %0, %1, %2" : "=v"(r) : "v"(a), "v"(b)); return r;
}
__device__ __forceinline__ double pk_fma(double a, double b, double c) {
    double r; asm("v_pk_fma_f32 %0, %1, %2, %3" : "=v"(r) : "v"(a), "v"(b), "v"(c)); return r;
}

// ---- f32 wave min via DPP: 6 steps x {dpp mov, v_min_f32}; uniform result. ----
// Identity (+inf) fed to invalid lanes via `old`. No NaNs in this kernel.
__device__ __forceinline__ float wave_min_f32(float v) {
    constexpr int PINF = 0x7F800000;
    int x = __float_as_int(v);
    #define DPP_MIN(CTRL, RM)                                                  \
        x = __float_as_int(fminf(__int_as_float(x), __int_as_float(            \
                __builtin_amdgcn_update_dpp(PINF, x, CTRL, RM, 0xF, false))));
    DPP_MIN(0x111, 0xF)  // row_shr:1
    DPP_MIN(0x112, 0xF)  // row_shr:2
    DPP_MIN(0x114, 0xF)  // row_shr:4
    DPP_MIN(0x118, 0xF)  // row_shr:8
    DPP_MIN(0x142, 0xA)  // row_bcast:15 -> rows 1,3
    DPP_MIN(0x143, 0xC)  // row_bcast:31 -> rows 2,3
    #undef DPP_MIN
    return __int_as_float(__builtin_amdgcn_readlane(x, 63));
}

__global__ __launch_bounds__(256) void knn_edge_kernel(const float* __restrict__ unit_pos,
                                                       int* __restrict__ out) {
    __shared__ double spd[NPER * DST];               // 36864 B
    float* sfl = reinterpret_cast<float*>(spd);

    const int wg  = blockIdx.x;        // 1024 WGs; 4 rows (waves) each
    const int seg = (wg * 4) >> 9;     // / NPER
    const int tid = threadIdx.x;

    // Stage segment positions, pair-SoA per candidate:
    // float layout [x0 x1 x2 x3 | y0..y3 | z0..z3 | pad x6], stride 18 floats.
    {
        const float4* g4 = reinterpret_cast<const float4*>(
            unit_pos + (size_t)seg * NPER * UU * 3);
        #pragma unroll
        for (int jj = 0; jj < 6; ++jj) {
            const int i4 = tid + 256 * jj;     // float4 index 0..1535
            const float4 v = g4[i4];
            const int c = i4 / 3;
            const int rem = (i4 - 3 * c) * 4;  // 0, 4, or 8
            const float vv[4] = {v.x, v.y, v.z, v.w};
            #pragma unroll
            for (int e = 0; e < 4; ++e) {
                const int j = rem + e, u = j / 3, ax = j - 3 * u;
                sfl[c * (2 * DST) + ax * 4 + u] = vv[e];
            }
        }
    }
    __syncthreads();

    const int wave = tid >> 6;
    const int lane = tid & 63;
    const int r_local  = (wg * 4 + wave) & (NPER - 1);
    const int r_global = seg * NPER + r_local;

    // Desync probe: waves leave the barrier aligned and run identical code, so
    // stall windows coincide and TLP can't hide them. Stagger 0..192 cycles.
    for (int s = 0; s < wave; ++s) __builtin_amdgcn_s_sleep(1);

    // Row units duplicated into pk pairs + norms (uniform broadcast reads).
    double xi_p[UU], yi_p[UU], zi_p[UU], ai_p[UU];
    {
        const float* rp = &sfl[r_local * (2 * DST)];
        #pragma unroll
        for (int u = 0; u < UU; ++u) {
            const float x = rp[0 * 4 + u], y = rp[1 * 4 + u], z = rp[2 * 4 + u];
            const float a = __fadd_rn(__fadd_rn(__fmul_rn(x, x), __fmul_rn(y, y)),
                                      __fmul_rn(z, z));
            xi_p[u] = mkpk(x, x); yi_p[u] = mkpk(y, y);
            zi_p[u] = mkpk(z, z); ai_p[u] = mkpk(a, a);
        }
    }
    const double m2 = mkpk(-2.0f, -2.0f);

    // Each lane owns candidates c = lane + 64*t. Packed math: halves are the
    // reference's exact f32 ops (left-assoc adds; fma(dot,-2,sum) ==
    // fsub(sum, fmul(2,dot)) since 2*dot is exact).
    float dist[8];
    #pragma unroll
    for (int t = 0; t < 8; ++t) {
        const int c = lane + 64 * t;
        const double* cp = &spd[c * DST];
        const double x01 = cp[0], x23 = cp[1];
        const double y01 = cp[2], y23 = cp[3];
        const double z01 = cp[4], z23 = cp[5];
        const double aj01 = pk_add(pk_add(pk_mul(x01, x01), pk_mul(y01, y01)),
                                   pk_mul(z01, z01));
        const double aj23 = pk_add(pk_add(pk_mul(x23, x23), pk_mul(y23, y23)),
                                   pk_mul(z23, z23));
        pk2 h[8];
        #pragma unroll
        for (int u = 0; u < UU; ++u) {
            const double dot01 = pk_add(pk_add(pk_mul(xi_p[u], x01),
                                               pk_mul(yi_p[u], y01)),
                                        pk_mul(zi_p[u], z01));
            const double dot23 = pk_add(pk_add(pk_mul(xi_p[u], x23),
                                               pk_mul(yi_p[u], y23)),
                                        pk_mul(zi_p[u], z23));
            h[u].d     = pk_fma(dot01, m2, pk_add(ai_p[u], aj01));
            h[4 + u].d = pk_fma(dot23, m2, pk_add(ai_p[u], aj23));
        }
        // Exact min over 16 d2; deferred clamp commutes with min bit-exactly.
        const float m01 = fminf(fminf(h[0].f[0], h[0].f[1]),
                                fminf(h[1].f[0], h[1].f[1]));
        const float m23 = fminf(fminf(h[2].f[0], h[2].f[1]),
                                fminf(h[3].f[0], h[3].f[1]));
        const float m45 = fminf(fminf(h[4].f[0], h[4].f[1]),
                                fminf(h[5].f[0], h[5].f[1]));
        const float m67 = fminf(fminf(h[6].f[0], h[6].f[1]),
                                fminf(h[7].f[0], h[7].f[1]));
        float m = fminf(fminf(m01, m23), fminf(m45, m67));
        m = fmaxf(m, 0.0f);
        // Same rounded sqrt as reference (collapses near-ties identically;
        // required so tie-break-by-col fires exactly where the reference ties).
        dist[t] = __fsqrt_rn(m);
    }

    // Selection: 16x { f32 wave-min -> ballot-match -> scalar smallest-col }.
    // Winner = smallest col with dist==m == reference stable (dist, edge-idx)
    // order. Cols are t-major (c = 64t+lane): scan t ascending, lowest lane.
    int vcol = 0;
    #pragma unroll 1
    for (int it = 0; it < KK; ++it) {
        float lm = dist[0];
        #pragma unroll
        for (int t = 1; t < 8; ++t) lm = fminf(lm, dist[t]);
        const float m = wave_min_f32(lm);              // uniform
        unsigned long long b[8];
        #pragma unroll
        for (int t = 0; t < 8; ++t) b[t] = __ballot(dist[t] == m);
        int wt = 7; unsigned long long bb = b[7];      // uniform scalar scan
        #pragma unroll
        for (int t = 6; t >= 0; --t) if (b[t] != 0ull) { wt = t; bb = b[t]; }
        const int wl = __ffsll((long long)bb) - 1;
        const int scol = (wt << 6) | wl;               // uniform winner col
        if (lane == it) vcol = scol;                   // scol uniform -> 1 cndmask
        #pragma unroll
        for (int t = 0; t < 8; ++t)                    // invalidate exactly one
            if (t == wt && lane == wl) dist[t] = __int_as_float(0x7F800000);
    }

    // Outputs concatenated flat: row_o[65536], col_o[65536], attr[65536] (int32).
    if (lane < KK) {
        const int o = r_global * KK + lane;
        out[o]          = r_global;
        out[NK + o]     = (seg * NPER) + vcol;
        out[2 * NK + o] = 0;
    }
}
} // namespace

extern "C" void kernel_launch(void* const* d_in, const int* in_sizes, int n_in,
                              void* d_out, int out_size, void* d_ws, size_t ws_size,
                              hipStream_t stream) {
    const float* unit_pos = (const float*)d_in[0];
    int* out = (int*)d_out;
    hipLaunchKernelGGL(knn_edge_kernel, dim3(NB / 4), dim3(256), 0, stream,
                       unit_pos, out);
}